// Round 13
// baseline (59.136 us; speedup 1.0000x reference)
//
#include <hip/hip_runtime.h>
#include <hip/hip_bf16.h>

#define C_IN  32
#define C_OUT 64
#define HH    64
#define WW    64
#define BREP  4   // DIAGNOSTIC: block-level replication (grid x4). Replica blocks
                  // run the byte-identical r10 program and store identical values
                  // -> deterministic. Lifts aeg_mfma above the 39us harness fills
                  // so rocprof top-5 finally shows its counters. Revert next round.

typedef __attribute__((ext_vector_type(8))) short short8v;
typedef __attribute__((ext_vector_type(4))) float f32x4;

static __device__ __forceinline__ unsigned short f2bf(float f) {
    unsigned u = __builtin_bit_cast(unsigned, f);
    unsigned r = (u + 0x7FFFu + ((u >> 16) & 1u)) >> 16;   // RNE
    return (unsigned short)r;
}
static __device__ __forceinline__ float bf2f(unsigned short b) {
    unsigned u = ((unsigned)b) << 16;
    return __builtin_bit_cast(float, u);
}

// ---------------------------------------------------------------------------
// Weight-product + B-fragment pack (cold kernel, unchanged from r10).
// W~_k = Ew(k) * (w_k if (p+k) odd), Ew(k) = prod_{j>=k, (p+j) even} w_j
// Bpk[p][part(h=0,l=1)][k(9)][octile(4)][lane(64)][j(8)]  (bf16)
//   lane = (ic>>3)*16 + (oc&15), j = ic&7, octile = oc>>4
// Per-parity half = 36864 shorts = 73728 B (contiguous).
// ---------------------------------------------------------------------------
__global__ void wprod_pack(const float* __restrict__ w, unsigned short* __restrict__ Bpk) {
    int t = blockIdx.x * 256 + threadIdx.x;
    if (t >= 2 * C_IN * C_OUT) return;
    int oc = t & 63;
    int ic = (t >> 6) & 31;
    int p  = t >> 11;
    const float* wp = w + (oc * C_IN + ic) * 9;
    float W[9];
    float Ew = 1.f;
    #pragma unroll
    for (int k = 8; k >= 0; --k) {
        float wk = wp[k];
        if (((p + k) & 1) == 0) { Ew *= wk; W[k] = Ew; }
        else                    { W[k] = wk * Ew; }
    }
    int lane = ((ic >> 3) << 4) + (oc & 15);
    int j    = ic & 7;
    int oct  = oc >> 4;
    #pragma unroll
    for (int k = 0; k < 9; ++k) {
        unsigned short hi = f2bf(W[k]);
        unsigned short lo = f2bf(W[k] - bf2f(hi));
        size_t ih = ((((size_t)(p * 2 + 0) * 9 + k) * 4 + oct) * 64 + lane) * 8 + j;
        size_t il = ((((size_t)(p * 2 + 1) * 9 + k) * 4 + oct) * 64 + lane) * 8 + j;
        Bpk[ih] = hi;
        Bpk[il] = lo;
    }
}

// ---------------------------------------------------------------------------
// GEMM body — VERIFIED orientation (A = X~, B = W~), byte-identical to r10.
// C = Xh*Wh + Xl*Wh + Xh*Wl  (Xl*Wl ~ 2^-18, dropped).
// C mapping (m89, e2e-verified): row=(l>>4)*4+r -> position, col=l&15 -> oc.
// ---------------------------------------------------------------------------
template<int P>
__device__ __forceinline__ void aeg_gemm(
    float (&xt)[8][9], const short8v* __restrict__ Bq,
    float* __restrict__ out, int n, int i0, int grp, int l)
{
    // X~: suffix products of odd-step x's; even steps multiply own x.
    #pragma unroll
    for (int a = 0; a < 8; ++a) {
        float Ox = 1.f;
        #pragma unroll
        for (int k = 8; k >= 0; --k) {
            if (((P + k) & 1) == 1) { Ox *= xt[a][k]; xt[a][k] = Ox; }
            else                    { xt[a][k] = xt[a][k] * Ox; }
        }
    }

    f32x4 acc[4];
    #pragma unroll
    for (int t = 0; t < 4; ++t) acc[t] = (f32x4){0.f, 0.f, 0.f, 0.f};

    #pragma unroll
    for (int k = 0; k < 9; ++k) {
        short8v ah, al;
        #pragma unroll
        for (int a = 0; a < 8; ++a) {
            float v  = xt[a][k];
            __hip_bfloat16 bh = __float2bfloat16(v);          // RNE
            float fh = __bfloat162float(bh);
            __hip_bfloat16 bl = __float2bfloat16(v - fh);
            ah[a] = (short)__builtin_bit_cast(unsigned short, bh);
            al[a] = (short)__builtin_bit_cast(unsigned short, bl);
        }
        #pragma unroll
        for (int t = 0; t < 4; ++t) {
            short8v bh = Bq[((0 * 9 + k) * 4 + t) * 64 + l];   // W~ hi
            short8v bl = Bq[((1 * 9 + k) * 4 + t) * 64 + l];   // W~ lo
            acc[t] = __builtin_amdgcn_mfma_f32_16x16x32_bf16(ah, bh, acc[t], 0, 0, 0);
            acc[t] = __builtin_amdgcn_mfma_f32_16x16x32_bf16(al, bh, acc[t], 0, 0, 0);
            acc[t] = __builtin_amdgcn_mfma_f32_16x16x32_bf16(ah, bl, acc[t], 0, 0, 0);
        }
    }

    // Scatter C: row = (l>>4)*4 + r (position), col = l&15 (oc low).
    int colc = l & 15;
    int rgrp = l >> 4;
    #pragma unroll
    for (int t = 0; t < 4; ++t) {
        int oc = t * 16 + colc;
        #pragma unroll
        for (int r = 0; r < 4; ++r) {
            int q = grp * 16 + rgrp * 4 + r;
            int i = i0 + (q >> 5);
            int j = 2 * (q & 31) + ((i + P) & 1);
            out[(((size_t)n * C_OUT + oc) * HH + i) * WW + j] = acc[t][r];
        }
    }
}

// ---------------------------------------------------------------------------
// Main kernel — byte-identical per-block program to r10 (24.6us, passed).
// Only change: blockIdx decode masks off the replication bits (bid & 511),
// so BREP replica blocks do identical work and store identical values.
// ---------------------------------------------------------------------------
__global__ __launch_bounds__(256, 2) void aeg_mfma(
    const float* __restrict__ x, const unsigned short* __restrict__ Bpk,
    float* __restrict__ out)
{
    __shared__ __attribute__((aligned(16))) unsigned short Blds[36864]; // 72KB

    int bid = blockIdx.x & 511;  // DIAGNOSTIC: replicas collapse to same work
    int pp  = bid & 1;           // parity (0..1)
    int br  = (bid >> 1) & 31;   // row-block (0..31), 2 rows each
    int n   = bid >> 6;          // batch (0..7)
    int i0  = br * 2;
    int tid = threadIdx.x;

    // Stage this parity's B half: 73728 B = 4608 x 16B, contiguous.
    {
        const f32x4* src = (const f32x4*)(Bpk + (size_t)pp * 36864);
        f32x4* dst = (f32x4*)Blds;
        #pragma unroll
        for (int i = 0; i < 18; ++i)
            dst[i * 256 + tid] = src[i * 256 + tid];
    }
    __syncthreads();

    int w   = __builtin_amdgcn_readfirstlane(tid >> 6);  // wave 0..3
    int grp = w;                 // M-group 0..3
    int l   = tid & 63;

    int qA = grp * 16 + (l & 15);
    int iA = i0 + (qA >> 5);
    int jA = 2 * (qA & 31) + ((iA + pp) & 1);
    int icb = (l >> 4) * 8;

    float xt[8][9];
    #pragma unroll
    for (int a = 0; a < 8; ++a) {
        const float* xb = x + ((size_t)n * C_IN + icb + a) * (HH * WW);
        #pragma unroll
        for (int di = 0; di < 3; ++di) {
            int ii = iA + di - 1;
            #pragma unroll
            for (int dj = 0; dj < 3; ++dj) {
                int jj = jA + dj - 1;
                bool ok = ((unsigned)ii < 64u) && ((unsigned)jj < 64u);
                xt[a][di * 3 + dj] = ok ? xb[ii * WW + jj] : 0.f;
            }
        }
    }

    const short8v* Bq = (const short8v*)Blds;
    if (pp == 0) aeg_gemm<0>(xt, Bq, out, n, i0, grp, l);
    else         aeg_gemm<1>(xt, Bq, out, n, i0, grp, l);
}

extern "C" void kernel_launch(void* const* d_in, const int* in_sizes, int n_in,
                              void* d_out, int out_size, void* d_ws, size_t ws_size,
                              hipStream_t stream) {
    const float* x = (const float*)d_in[0];
    const float* w = (const float*)d_in[1];
    float* out = (float*)d_out;
    unsigned short* Bpk = (unsigned short*)d_ws;   // 147,456 bytes

    wprod_pack<<<16, 256, 0, stream>>>(w, Bpk);
    aeg_mfma<<<512 * BREP, 256, 0, stream>>>(x, Bpk, out);
}

// Round 14
// 22.528 us; speedup vs baseline: 2.6250x; 2.6250x over previous
//
#include <hip/hip_runtime.h>
#include <hip/hip_bf16.h>

#define C_IN  32
#define C_OUT 64
#define HH    64
#define WW    64

typedef __attribute__((ext_vector_type(8))) short short8v;
typedef __attribute__((ext_vector_type(4))) float f32x4;

static __device__ __forceinline__ unsigned short f2bf(float f) {
    unsigned u = __builtin_bit_cast(unsigned, f);
    unsigned r = (u + 0x7FFFu + ((u >> 16) & 1u)) >> 16;   // RNE
    return (unsigned short)r;
}
static __device__ __forceinline__ float bf2f(unsigned short b) {
    unsigned u = ((unsigned)b) << 16;
    return __builtin_bit_cast(float, u);
}

// ---------------------------------------------------------------------------
// Weight-product + B-fragment pack (cold kernel, unchanged from r10/r13).
// W~_k = Ew(k) * (w_k if (p+k) odd), Ew(k) = prod_{j>=k, (p+j) even} w_j
// Bpk[p][part(h=0,l=1)][k(9)][octile(4)][lane(64)][j(8)]  (bf16)
//   lane = (ic>>3)*16 + (oc&15), j = ic&7, octile = oc>>4
// Per-parity half = 36864 shorts = 73728 B (contiguous).
// ---------------------------------------------------------------------------
__global__ void wprod_pack(const float* __restrict__ w, unsigned short* __restrict__ Bpk) {
    int t = blockIdx.x * 256 + threadIdx.x;
    if (t >= 2 * C_IN * C_OUT) return;
    int oc = t & 63;
    int ic = (t >> 6) & 31;
    int p  = t >> 11;
    const float* wp = w + (oc * C_IN + ic) * 9;
    float W[9];
    float Ew = 1.f;
    #pragma unroll
    for (int k = 8; k >= 0; --k) {
        float wk = wp[k];
        if (((p + k) & 1) == 0) { Ew *= wk; W[k] = Ew; }
        else                    { W[k] = wk * Ew; }
    }
    int lane = ((ic >> 3) << 4) + (oc & 15);
    int j    = ic & 7;
    int oct  = oc >> 4;
    #pragma unroll
    for (int k = 0; k < 9; ++k) {
        unsigned short hi = f2bf(W[k]);
        unsigned short lo = f2bf(W[k] - bf2f(hi));
        size_t ih = ((((size_t)(p * 2 + 0) * 9 + k) * 4 + oct) * 64 + lane) * 8 + j;
        size_t il = ((((size_t)(p * 2 + 1) * 9 + k) * 4 + oct) * 64 + lane) * 8 + j;
        Bpk[ih] = hi;
        Bpk[il] = lo;
    }
}

// ---------------------------------------------------------------------------
// GEMM body — VERIFIED orientation (A = X~, B = W~). Computes acc only
// (store moved to the caller's LDS-staged coalesced epilogue).
// C = Xh*Wh + Xl*Wh + Xh*Wl  (Xl*Wl ~ 2^-18, dropped).
// C mapping (m89, e2e-verified): row=(l>>4)*4+r -> position, col=l&15 -> oc.
// ---------------------------------------------------------------------------
template<int P>
__device__ __forceinline__ void aeg_gemm(
    float (&xt)[8][9], const short8v* __restrict__ Bq, f32x4 (&acc)[4], int l)
{
    // X~: suffix products of odd-step x's; even steps multiply own x.
    #pragma unroll
    for (int a = 0; a < 8; ++a) {
        float Ox = 1.f;
        #pragma unroll
        for (int k = 8; k >= 0; --k) {
            if (((P + k) & 1) == 1) { Ox *= xt[a][k]; xt[a][k] = Ox; }
            else                    { xt[a][k] = xt[a][k] * Ox; }
        }
    }

    #pragma unroll
    for (int t = 0; t < 4; ++t) acc[t] = (f32x4){0.f, 0.f, 0.f, 0.f};

    #pragma unroll
    for (int k = 0; k < 9; ++k) {
        short8v ah, al;
        #pragma unroll
        for (int a = 0; a < 8; ++a) {
            float v  = xt[a][k];
            __hip_bfloat16 bh = __float2bfloat16(v);          // RNE
            float fh = __bfloat162float(bh);
            __hip_bfloat16 bl = __float2bfloat16(v - fh);
            ah[a] = (short)__builtin_bit_cast(unsigned short, bh);
            al[a] = (short)__builtin_bit_cast(unsigned short, bl);
        }
        #pragma unroll
        for (int t = 0; t < 4; ++t) {
            short8v bh = Bq[((0 * 9 + k) * 4 + t) * 64 + l];   // W~ hi
            short8v bl = Bq[((1 * 9 + k) * 4 + t) * 64 + l];   // W~ lo
            acc[t] = __builtin_amdgcn_mfma_f32_16x16x32_bf16(ah, bh, acc[t], 0, 0, 0);
            acc[t] = __builtin_amdgcn_mfma_f32_16x16x32_bf16(al, bh, acc[t], 0, 0, 0);
            acc[t] = __builtin_amdgcn_mfma_f32_16x16x32_bf16(ah, bl, acc[t], 0, 0, 0);
        }
    }
}

// ---------------------------------------------------------------------------
// Main kernel: block = 1 n x 2 rows x 64 cols x ONE parity, 256 thr = 4
// waves (structure verified r10/r13). NEW: epilogue stages C through the
// retired B-LDS region and emits structured stores — each store inst's 64
// lanes cover one oc-plane's 2-row stripe (j stride 2) = 4-8 cache lines,
// vs 64 lines for the old direct scatter (16x fewer line-visits, full-line
// HBM writes).
// ---------------------------------------------------------------------------
__global__ __launch_bounds__(256, 2) void aeg_mfma(
    const float* __restrict__ x, const unsigned short* __restrict__ Bpk,
    float* __restrict__ out)
{
    __shared__ __attribute__((aligned(16))) unsigned short Blds[36864]; // 72KB

    int bid = blockIdx.x;
    int pp  = bid & 1;           // parity (0..1)
    int br  = (bid >> 1) & 31;   // row-block (0..31), 2 rows each
    int n   = bid >> 6;          // batch (0..7)
    int i0  = br * 2;
    int tid = threadIdx.x;

    // Stage this parity's B half: 73728 B = 4608 x 16B, contiguous.
    {
        const f32x4* src = (const f32x4*)(Bpk + (size_t)pp * 36864);
        f32x4* dst = (f32x4*)Blds;
        #pragma unroll
        for (int i = 0; i < 18; ++i)
            dst[i * 256 + tid] = src[i * 256 + tid];
    }
    __syncthreads();

    int w   = __builtin_amdgcn_readfirstlane(tid >> 6);  // wave 0..3
    int grp = w;                 // M-group 0..3
    int l   = tid & 63;

    int qA = grp * 16 + (l & 15);
    int iA = i0 + (qA >> 5);
    int jA = 2 * (qA & 31) + ((iA + pp) & 1);
    int icb = (l >> 4) * 8;

    float xt[8][9];
    #pragma unroll
    for (int a = 0; a < 8; ++a) {
        const float* xb = x + ((size_t)n * C_IN + icb + a) * (HH * WW);
        #pragma unroll
        for (int di = 0; di < 3; ++di) {
            int ii = iA + di - 1;
            #pragma unroll
            for (int dj = 0; dj < 3; ++dj) {
                int jj = jA + dj - 1;
                bool ok = ((unsigned)ii < 64u) && ((unsigned)jj < 64u);
                xt[a][di * 3 + dj] = ok ? xb[ii * WW + jj] : 0.f;
            }
        }
    }

    const short8v* Bq = (const short8v*)Blds;
    f32x4 acc[4];
    if (pp == 0) aeg_gemm<0>(xt, Bq, acc, l);
    else         aeg_gemm<1>(xt, Bq, acc, l);

    // ---- Epilogue: coalesce C through LDS (B region is dead after here) ----
    __syncthreads();                       // all waves done reading Blds
    float* cls = (float*)Blds;             // C-tile: cls[oc*65 + q], 16.6KB

    {
        int colc = l & 15;
        int rgrp = l >> 4;
        #pragma unroll
        for (int t = 0; t < 4; ++t) {
            int oc = t * 16 + colc;
            #pragma unroll
            for (int r = 0; r < 4; ++r) {
                int q = grp * 16 + rgrp * 4 + r;   // position 0..63 in block
                cls[oc * 65 + q] = acc[t][r];
            }
        }
    }
    __syncthreads();

    // Structured write-out: lane -> q, 64 lanes = one oc's 2-row stripe.
    #pragma unroll
    for (int v = 0; v < 16; ++v) {
        int flat = v * 256 + tid;          // 0..4095
        int oc   = flat >> 6;
        int q    = flat & 63;
        int i    = i0 + (q >> 5);
        int j    = 2 * (q & 31) + ((i + pp) & 1);
        out[(((size_t)n * C_OUT + oc) * HH + i) * WW + j] = cls[oc * 65 + q];
    }
}

extern "C" void kernel_launch(void* const* d_in, const int* in_sizes, int n_in,
                              void* d_out, int out_size, void* d_ws, size_t ws_size,
                              hipStream_t stream) {
    const float* x = (const float*)d_in[0];
    const float* w = (const float*)d_in[1];
    float* out = (float*)d_out;
    unsigned short* Bpk = (unsigned short*)d_ws;   // 147,456 bytes

    wprod_pack<<<16, 256, 0, stream>>>(w, Bpk);
    aeg_mfma<<<512, 256, 0, stream>>>(x, Bpk, out);
}

// Round 15
// 20.148 us; speedup vs baseline: 2.9351x; 1.1181x over previous
//
#include <hip/hip_runtime.h>
#include <hip/hip_bf16.h>

#define C_IN  32
#define C_OUT 64
#define HH    64
#define WW    64

typedef __attribute__((ext_vector_type(8))) short short8v;
typedef __attribute__((ext_vector_type(4))) float f32x4;

static __device__ __forceinline__ unsigned short f2bf(float f) {
    unsigned u = __builtin_bit_cast(unsigned, f);
    unsigned r = (u + 0x7FFFu + ((u >> 16) & 1u)) >> 16;   // RNE
    return (unsigned short)r;
}
static __device__ __forceinline__ float bf2f(unsigned short b) {
    unsigned u = ((unsigned)b) << 16;
    return __builtin_bit_cast(float, u);
}

// ---------------------------------------------------------------------------
// FUSED W~ pack: computed per-block directly into LDS (no global round trip,
// no separate dispatch). Thread = (oct = tid>>6, lane = tid&63) covers
// oc = oct*16 + (lane&15), ic = (lane>>4)*8 .. +7  (full parity half).
// W~_k = Ew(k) * (w_k if (P+k) odd), Ew(k) = prod_{j>=k, (P+j) even} w_j
// LDS layout (identical to r10-r14 Bpk half):
//   Blds16[((part*9 + k)*4 + oct)*64 + lane] = short8 {8 ics' bf16}  (16B)
// Same f2bf RNE math as the old wprod_pack -> bit-identical B values.
// ---------------------------------------------------------------------------
template<int P>
__device__ __forceinline__ void packB(const float* __restrict__ w,
                                      short8v* __restrict__ Blds16, int tid)
{
    int oct  = tid >> 6;
    int lane = tid & 63;
    int oc   = oct * 16 + (lane & 15);
    int icb  = (lane >> 4) * 8;

    // 72 consecutive floats = 8 ic-rows x 9 taps; base (oc*32+icb)*9 is
    // divisible by 4 (72*g + 288*oc) -> 16B-aligned: 18 dwordx4 loads.
    float wv[72];
    const f32x4* src = (const f32x4*)(w + ((size_t)oc * C_IN + icb) * 9);
    #pragma unroll
    for (int i = 0; i < 18; ++i) {
        f32x4 v = src[i];
        wv[4 * i + 0] = v.x; wv[4 * i + 1] = v.y;
        wv[4 * i + 2] = v.z; wv[4 * i + 3] = v.w;
    }

    // Suffix products in place (identical to old wprod_pack loop).
    #pragma unroll
    for (int a = 0; a < 8; ++a) {
        float Ew = 1.f;
        #pragma unroll
        for (int k = 8; k >= 0; --k) {
            float wk = wv[9 * a + k];
            if (((P + k) & 1) == 0) { Ew *= wk; wv[9 * a + k] = Ew; }
            else                    { wv[9 * a + k] = wk * Ew; }
        }
    }

    // Assemble + write: 9k x {hi, lo} ds_write_b128.
    #pragma unroll
    for (int k = 0; k < 9; ++k) {
        short8v vh, vl;
        #pragma unroll
        for (int a = 0; a < 8; ++a) {
            float v  = wv[9 * a + k];
            unsigned short h = f2bf(v);
            vh[a] = (short)h;
            vl[a] = (short)f2bf(v - bf2f(h));
        }
        Blds16[((0 * 9 + k) * 4 + oct) * 64 + lane] = vh;
        Blds16[((1 * 9 + k) * 4 + oct) * 64 + lane] = vl;
    }
}

// ---------------------------------------------------------------------------
// GEMM body — VERIFIED orientation (A = X~, B = W~), unchanged from r14.
// C = Xh*Wh + Xl*Wh + Xh*Wl  (Xl*Wl ~ 2^-18, dropped).
// C mapping (m89, e2e-verified): row=(l>>4)*4+r -> position, col=l&15 -> oc.
// ---------------------------------------------------------------------------
template<int P>
__device__ __forceinline__ void aeg_gemm(
    float (&xt)[8][9], const short8v* __restrict__ Bq, f32x4 (&acc)[4], int l)
{
    // X~: suffix products of odd-step x's; even steps multiply own x.
    #pragma unroll
    for (int a = 0; a < 8; ++a) {
        float Ox = 1.f;
        #pragma unroll
        for (int k = 8; k >= 0; --k) {
            if (((P + k) & 1) == 1) { Ox *= xt[a][k]; xt[a][k] = Ox; }
            else                    { xt[a][k] = xt[a][k] * Ox; }
        }
    }

    #pragma unroll
    for (int t = 0; t < 4; ++t) acc[t] = (f32x4){0.f, 0.f, 0.f, 0.f};

    #pragma unroll
    for (int k = 0; k < 9; ++k) {
        short8v ah, al;
        #pragma unroll
        for (int a = 0; a < 8; ++a) {
            float v  = xt[a][k];
            __hip_bfloat16 bh = __float2bfloat16(v);          // RNE
            float fh = __bfloat162float(bh);
            __hip_bfloat16 bl = __float2bfloat16(v - fh);
            ah[a] = (short)__builtin_bit_cast(unsigned short, bh);
            al[a] = (short)__builtin_bit_cast(unsigned short, bl);
        }
        #pragma unroll
        for (int t = 0; t < 4; ++t) {
            short8v bh = Bq[((0 * 9 + k) * 4 + t) * 64 + l];   // W~ hi
            short8v bl = Bq[((1 * 9 + k) * 4 + t) * 64 + l];   // W~ lo
            acc[t] = __builtin_amdgcn_mfma_f32_16x16x32_bf16(ah, bh, acc[t], 0, 0, 0);
            acc[t] = __builtin_amdgcn_mfma_f32_16x16x32_bf16(al, bh, acc[t], 0, 0, 0);
            acc[t] = __builtin_amdgcn_mfma_f32_16x16x32_bf16(ah, bl, acc[t], 0, 0, 0);
        }
    }
}

// ---------------------------------------------------------------------------
// Main (single) kernel: block = 1 n x 2 rows x 64 cols x ONE parity, 256
// threads = 4 waves. Phase 1: fused in-LDS W~ pack (above). Phase 2 (after
// one barrier): x-tap loads, 3-term MFMA, LDS-coalesced epilogue — all
// byte-identical to r14 (22.5us, passed).
// ---------------------------------------------------------------------------
__global__ __launch_bounds__(256, 2) void aeg_mfma(
    const float* __restrict__ x, const float* __restrict__ w,
    float* __restrict__ out)
{
    __shared__ __attribute__((aligned(16))) unsigned short Blds[36864]; // 72KB

    int bid = blockIdx.x;
    int pp  = bid & 1;           // parity (0..1)
    int br  = (bid >> 1) & 31;   // row-block (0..31), 2 rows each
    int n   = bid >> 6;          // batch (0..7)
    int i0  = br * 2;
    int tid = threadIdx.x;

    if (pp == 0) packB<0>(w, (short8v*)Blds, tid);
    else         packB<1>(w, (short8v*)Blds, tid);
    __syncthreads();

    int wv  = __builtin_amdgcn_readfirstlane(tid >> 6);  // wave 0..3
    int grp = wv;                // M-group 0..3
    int l   = tid & 63;

    int qA = grp * 16 + (l & 15);
    int iA = i0 + (qA >> 5);
    int jA = 2 * (qA & 31) + ((iA + pp) & 1);
    int icb = (l >> 4) * 8;

    float xt[8][9];
    #pragma unroll
    for (int a = 0; a < 8; ++a) {
        const float* xb = x + ((size_t)n * C_IN + icb + a) * (HH * WW);
        #pragma unroll
        for (int di = 0; di < 3; ++di) {
            int ii = iA + di - 1;
            #pragma unroll
            for (int dj = 0; dj < 3; ++dj) {
                int jj = jA + dj - 1;
                bool ok = ((unsigned)ii < 64u) && ((unsigned)jj < 64u);
                xt[a][di * 3 + dj] = ok ? xb[ii * WW + jj] : 0.f;
            }
        }
    }

    const short8v* Bq = (const short8v*)Blds;
    f32x4 acc[4];
    if (pp == 0) aeg_gemm<0>(xt, Bq, acc, l);
    else         aeg_gemm<1>(xt, Bq, acc, l);

    // ---- Epilogue: coalesce C through LDS (B region is dead after here) ----
    __syncthreads();                       // all waves done reading Blds
    float* cls = (float*)Blds;             // C-tile: cls[oc*65 + q], 16.6KB

    {
        int colc = l & 15;
        int rgrp = l >> 4;
        #pragma unroll
        for (int t = 0; t < 4; ++t) {
            int oc = t * 16 + colc;
            #pragma unroll
            for (int r = 0; r < 4; ++r) {
                int q = grp * 16 + rgrp * 4 + r;   // position 0..63 in block
                cls[oc * 65 + q] = acc[t][r];
            }
        }
    }
    __syncthreads();

    // Structured write-out: lane -> q, 64 lanes = one oc's 2-row stripe.
    #pragma unroll
    for (int v = 0; v < 16; ++v) {
        int flat = v * 256 + tid;          // 0..4095
        int oc   = flat >> 6;
        int q    = flat & 63;
        int i    = i0 + (q >> 5);
        int j    = 2 * (q & 31) + ((i + pp) & 1);
        out[(((size_t)n * C_OUT + oc) * HH + i) * WW + j] = cls[oc * 65 + q];
    }
}

extern "C" void kernel_launch(void* const* d_in, const int* in_sizes, int n_in,
                              void* d_out, int out_size, void* d_ws, size_t ws_size,
                              hipStream_t stream) {
    const float* x = (const float*)d_in[0];
    const float* w = (const float*)d_in[1];
    float* out = (float*)d_out;
    (void)d_ws; (void)ws_size;

    aeg_mfma<<<512, 256, 0, stream>>>(x, w, out);
}